// Round 12
// baseline (124.532 us; speedup 1.0000x reference)
//
#include <hip/hip_runtime.h>

constexpr int   N    = 8192;
constexpr int   NB   = 256;                 // z-buckets per set
constexpr float ZLO  = -4.5f, ZHI = 4.5f;
constexpr float WINV = NB / (ZHI - ZLO);
constexpr float W    = (ZHI - ZLO) / NB;
constexpr double SCALE = 274877906944.0;    // 2^38 fixed-point for exact sum

__device__ __forceinline__ int zbucket(float z) {
    int b = (int)((z - ZLO) * WINV);
    return min(max(b, 0), NB - 1);
}

// One block: LDS histogram (512 buckets: set0 then set1), Hillis-Steele scan,
// scatter to sorted[] (set0 slots [0,N), set1 [N,2N)), publish offs[513].
__global__ __launch_bounds__(1024) void zsort(
    const float* __restrict__ pred, const float* __restrict__ label,
    float4* __restrict__ sorted, unsigned int* __restrict__ offs)
{
    __shared__ unsigned int cnt[512], pre[512], cur[512];
    int t = threadIdx.x;
    if (t < 512) cnt[t] = 0;
    __syncthreads();

    for (int i = t; i < 2 * N; i += 1024) {          // count
        const float* src = (i < N) ? pred : label;
        int j = i & (N - 1);
        int b = zbucket(src[3*j + 2]) + ((i >= N) ? NB : 0);
        atomicAdd(&cnt[b], 1u);
    }
    __syncthreads();

    if (t < 512) pre[t] = cnt[t];                    // inclusive scan, 9 steps
    __syncthreads();
    for (int s = 1; s < 512; s <<= 1) {
        unsigned int add = (t < 512 && t >= s) ? pre[t - s] : 0u;
        __syncthreads();
        if (t < 512) pre[t] += add;
        __syncthreads();
    }
    if (t < 512) {
        unsigned int ex = pre[t] - cnt[t];           // exclusive
        cur[t]  = ex;
        offs[t] = ex;
        if (t == 511) offs[512] = pre[511];          // = 2N
    }
    __syncthreads();

    for (int i = t; i < 2 * N; i += 1024) {          // scatter
        const float* src = (i < N) ? pred : label;
        int j = i & (N - 1);
        float x = src[3*j], y = src[3*j + 1], z = src[3*j + 2];
        int b = zbucket(z) + ((i >= N) ? NB : 0);
        unsigned int slot = atomicAdd(&cur[b], 1u);
        sorted[slot] = make_float4(x, y, z, 0.f);
    }
}

// 8 lanes per query. Scan own bucket, then rings outward; stop a side when
// (q.z - near_edge)^2 >= group best. Exact: d >= |dz| and best only shrinks.
__global__ __launch_bounds__(256) void zquery(
    const float4* __restrict__ sorted, const unsigned int* __restrict__ offs,
    float* __restrict__ dout)
{
    int qid = (blockIdx.x * 256 + threadIdx.x) >> 3;   // [0, 2N)
    int sub = threadIdx.x & 7;
    float4 q = sorted[qid];
    int tb = (qid < N) ? NB : 0;                       // search the OTHER set
    int bq = zbucket(q.z);
    float best2 = 3.4e38f;

    {   // own bucket
        int s0 = offs[tb + bq], s1 = offs[tb + bq + 1];
        for (int i = s0 + sub; i < (int)s1; i += 8) {
            float4 p = sorted[i];
            float dx = q.x - p.x, dy = q.y - p.y, dz = q.z - p.z;
            best2 = fminf(best2, dx*dx + dy*dy + dz*dz);
        }
    }
    bool dn = (bq == 0), up = (bq == NB - 1);
    for (int r = 1; r < NB && !(dn && up); ++r) {
        best2 = fminf(best2, __shfl_xor(best2, 1));    // group min (8 lanes)
        best2 = fminf(best2, __shfl_xor(best2, 2));
        best2 = fminf(best2, __shfl_xor(best2, 4));
        if (!dn) {
            int b = bq - r;
            if (b < 0) dn = true;
            else {
                float dz = q.z - (ZLO + (b + 1) * W);  // dist to bucket hi edge
                if (dz > 0.f && dz * dz >= best2) dn = true;
                else {
                    int s0 = offs[tb + b], s1 = offs[tb + b + 1];
                    for (int i = s0 + sub; i < (int)s1; i += 8) {
                        float4 p = sorted[i];
                        float dx = q.x - p.x, dy = q.y - p.y, dzz = q.z - p.z;
                        best2 = fminf(best2, dx*dx + dy*dy + dzz*dzz);
                    }
                }
            }
        }
        if (!up) {
            int b = bq + r;
            if (b >= NB) up = true;
            else {
                float dz = (ZLO + b * W) - q.z;        // dist to bucket lo edge
                if (dz > 0.f && dz * dz >= best2) up = true;
                else {
                    int s0 = offs[tb + b], s1 = offs[tb + b + 1];
                    for (int i = s0 + sub; i < (int)s1; i += 8) {
                        float4 p = sorted[i];
                        float dx = q.x - p.x, dy = q.y - p.y, dzz = q.z - p.z;
                        best2 = fminf(best2, dx*dx + dy*dy + dzz*dzz);
                    }
                }
            }
        }
    }
    best2 = fminf(best2, __shfl_xor(best2, 1));
    best2 = fminf(best2, __shfl_xor(best2, 2));
    best2 = fminf(best2, __shfl_xor(best2, 4));
    if (sub == 0) dout[qid] = sqrtf(best2);
}

// Fixed-point i64 partial sums (order-exact under within-bucket permutation).
__global__ __launch_bounds__(256) void dreduce(
    const float* __restrict__ dout, long long* __restrict__ part)
{
    long long s = 0;
    #pragma unroll
    for (int k = 0; k < 4; ++k) {
        float d = dout[blockIdx.x * 1024 + k * 256 + threadIdx.x];
        s += (long long)((double)d * SCALE);
    }
    for (int off = 32; off; off >>= 1) s += __shfl_down(s, off);
    __shared__ long long r2[4];
    if ((threadIdx.x & 63) == 0) r2[threadIdx.x >> 6] = s;
    __syncthreads();
    if (threadIdx.x == 0) part[blockIdx.x] = r2[0] + r2[1] + r2[2] + r2[3];
}

__global__ __launch_bounds__(64) void dfinal(
    const long long* __restrict__ part, float* __restrict__ out)
{
    long long s = (threadIdx.x < 16) ? part[threadIdx.x] : 0;
    for (int off = 32; off; off >>= 1) s += __shfl_down(s, off);
    if (threadIdx.x == 0)
        out[0] = (float)((double)s / SCALE / (double)N);  // mean_x + mean_y
}

extern "C" void kernel_launch(void* const* d_in, const int* in_sizes, int n_in,
                              void* d_out, int out_size, void* d_ws, size_t ws_size,
                              hipStream_t stream) {
    const float* pred  = (const float*)d_in[0];
    const float* label = (const float*)d_in[1];
    float* out = (float*)d_out;

    char* ws = (char*)d_ws;
    float4*       sorted = (float4*)ws;                          // 256 KB
    float*        dout   = (float*)(ws + 256 * 1024);            // 64 KB
    long long*    part   = (long long*)(ws + 320 * 1024);        // 128 B
    unsigned int* offs   = (unsigned int*)(ws + 321 * 1024);     // 2052 B

    zsort  <<<dim3(1),   dim3(1024), 0, stream>>>(pred, label, sorted, offs);
    zquery <<<dim3(512), dim3(256),  0, stream>>>(sorted, offs, dout);
    dreduce<<<dim3(16),  dim3(256),  0, stream>>>(dout, part);
    dfinal <<<dim3(1),   dim3(64),   0, stream>>>(part, out);
}

// Round 13
// 113.485 us; speedup vs baseline: 1.0973x; 1.0973x over previous
//
#include <hip/hip_runtime.h>

constexpr int    N    = 8192;
constexpr int    NB   = 256;                 // z-buckets per set
constexpr float  ZLO  = -4.5f, ZHI = 4.5f;
constexpr float  WINV = NB / (ZHI - ZLO);
constexpr double SCALE = 274877906944.0;     // 2^38 fixed-point (order-exact sum)

__device__ __forceinline__ int zbucket(float z) {
    float t = fminf(fmaxf((z - ZLO) * WINV, 0.0f), (float)(NB - 1));
    return (int)t;   // monotone, clamped, no int-overflow path
}

__global__ __launch_bounds__(512) void zinit(unsigned int* __restrict__ cnt,
                                             unsigned int* __restrict__ counter) {
    cnt[threadIdx.x] = 0u;
    if (threadIdx.x == 0) *counter = 0u;
}

// 16 blocks: LDS histogram, merge to global cnt[512] (set0 then set1).
__global__ __launch_bounds__(256) void zhist(
    const float* __restrict__ pred, const float* __restrict__ label,
    unsigned int* __restrict__ cnt)
{
    __shared__ unsigned int h[2 * NB];
    for (int t = threadIdx.x; t < 2 * NB; t += 256) h[t] = 0u;
    __syncthreads();
    #pragma unroll
    for (int k = 0; k < 4; ++k) {
        int i = blockIdx.x * 1024 + k * 256 + threadIdx.x;
        const float* s = (i < N) ? pred : label;
        int j = i & (N - 1);
        int b = zbucket(s[3*j + 2]) + ((i >= N) ? NB : 0);
        atomicAdd(&h[b], 1u);
    }
    __syncthreads();
    for (int t = threadIdx.x; t < 2 * NB; t += 256)
        if (h[t]) atomicAdd(&cnt[t], h[t]);
}

// 1 block: Hillis-Steele scan of 512 counts -> offs[513], cur seeded.
__global__ __launch_bounds__(512) void zscan(
    const unsigned int* __restrict__ cnt, unsigned int* __restrict__ offs,
    unsigned int* __restrict__ cur)
{
    __shared__ unsigned int pre[512];
    int t = threadIdx.x;
    unsigned int c = cnt[t];
    pre[t] = c;
    __syncthreads();
    for (int s = 1; s < 512; s <<= 1) {
        unsigned int add = (t >= s) ? pre[t - s] : 0u;
        __syncthreads();
        pre[t] += add;
        __syncthreads();
    }
    unsigned int ex = pre[t] - c;
    offs[t] = ex;  cur[t] = ex;
    if (t == 511) offs[512] = pre[511];          // = 2N
}

// 16 blocks: scatter points into z-sorted order (set0 [0,N), set1 [N,2N)).
__global__ __launch_bounds__(256) void zscatter(
    const float* __restrict__ pred, const float* __restrict__ label,
    unsigned int* __restrict__ cur, float4* __restrict__ sorted)
{
    #pragma unroll
    for (int k = 0; k < 4; ++k) {
        int i = blockIdx.x * 1024 + k * 256 + threadIdx.x;
        const float* s = (i < N) ? pred : label;
        int j = i & (N - 1);
        float x = s[3*j], y = s[3*j + 1], z = s[3*j + 2];
        int b = zbucket(z) + ((i >= N) ? NB : 0);
        unsigned int slot = atomicAdd(&cur[b], 1u);
        sorted[slot] = make_float4(x, y, z, 0.f);
    }
}

// One WAVE per query (4/block). Phase A: seed bound from nearest nonempty
// bucket span. Phase B: coalesced scan of the exact z-window. All branches
// wave-uniform; candidate loads 64-wide coalesced. Last block sums partials.
__global__ __launch_bounds__(256) void zquery(
    const float4* __restrict__ sorted, const unsigned int* __restrict__ offs,
    long long* __restrict__ part, unsigned int* __restrict__ counter,
    float* __restrict__ out)
{
    int wid = threadIdx.x >> 6, lane = threadIdx.x & 63;
    int qid = blockIdx.x * 4 + wid;                 // [0, 2N)
    float4 q = sorted[qid];
    int tb = (qid < N) ? NB : 0;                    // search the OTHER set
    int bq = zbucket(q.z);

    int lo = max(bq - 1, 0), hi = min(bq + 1, NB - 1);
    unsigned int a0 = offs[tb + lo], a1 = offs[tb + hi + 1];
    int w = 1;
    while (a0 == a1 && (lo > 0 || hi < NB - 1)) {   // rare: widen to nonempty
        w <<= 1;
        lo = max(bq - w, 0); hi = min(bq + w, NB - 1);
        a0 = offs[tb + lo]; a1 = offs[tb + hi + 1];
    }
    float best2 = 3.4e38f;
    for (int i = (int)a0 + lane; i < (int)a1; i += 64) {
        float4 p = sorted[i];
        float dx = q.x - p.x, dy = q.y - p.y, dz = q.z - p.z;
        best2 = fminf(best2, dx*dx + dy*dy + dz*dz);
    }
    #pragma unroll
    for (int off = 32; off; off >>= 1)
        best2 = fminf(best2, __shfl_xor(best2, off));

    float rad = sqrtf(best2);
    int l2 = zbucket(q.z - rad), h2 = zbucket(q.z + rad);
    unsigned int s0 = offs[tb + l2], s1 = offs[tb + h2 + 1];
    if (s0 < a0 || s1 > a1) {                       // window wider than seed
        for (int i = (int)s0 + lane; i < (int)s1; i += 64) {
            float4 p = sorted[i];
            float dx = q.x - p.x, dy = q.y - p.y, dz = q.z - p.z;
            best2 = fminf(best2, dx*dx + dy*dy + dz*dz);
        }
        #pragma unroll
        for (int off = 32; off; off >>= 1)
            best2 = fminf(best2, __shfl_xor(best2, off));
    }

    __shared__ long long w4[4];
    __shared__ unsigned int isLast;
    if (lane == 0)
        w4[wid] = (long long)((double)sqrtf(best2) * SCALE);
    __syncthreads();
    if (threadIdx.x == 0) {
        part[blockIdx.x] = w4[0] + w4[1] + w4[2] + w4[3];
        __threadfence();
        unsigned int old = atomicAdd(counter, 1u);
        isLast = (old == 4095u) ? 1u : 0u;          // counter seeded 0 by zinit
    }
    __syncthreads();
    if (!isLast) return;

    __threadfence();
    long long s = 0;
    for (int k = 0; k < 16; ++k) {                  // fixed order per thread
        int idx = k * 256 + threadIdx.x;
        s += __hip_atomic_load(&part[idx], __ATOMIC_RELAXED,
                               __HIP_MEMORY_SCOPE_AGENT);
    }
    for (int off = 32; off; off >>= 1) s += __shfl_down(s, off);
    __shared__ long long r2[4];
    if ((threadIdx.x & 63) == 0) r2[threadIdx.x >> 6] = s;
    __syncthreads();
    if (threadIdx.x == 0)
        out[0] = (float)(((double)(r2[0] + r2[1] + r2[2] + r2[3]))
                         / SCALE / (double)N);      // mean_x + mean_y
}

extern "C" void kernel_launch(void* const* d_in, const int* in_sizes, int n_in,
                              void* d_out, int out_size, void* d_ws, size_t ws_size,
                              hipStream_t stream) {
    const float* pred  = (const float*)d_in[0];
    const float* label = (const float*)d_in[1];
    float* out = (float*)d_out;

    char* ws = (char*)d_ws;
    float4*       sorted  = (float4*)ws;                         // 256 KB
    long long*    part    = (long long*)(ws + 262144);           // 32 KB
    unsigned int* offs    = (unsigned int*)(ws + 294912);        // 2052 B
    unsigned int* cnt     = (unsigned int*)(ws + 296964);        // 2048 B
    unsigned int* cur     = (unsigned int*)(ws + 299012);        // 2048 B
    unsigned int* counter = (unsigned int*)(ws + 301060);        // 4 B

    zinit   <<<dim3(1),    dim3(512), 0, stream>>>(cnt, counter);
    zhist   <<<dim3(16),   dim3(256), 0, stream>>>(pred, label, cnt);
    zscan   <<<dim3(1),    dim3(512), 0, stream>>>(cnt, offs, cur);
    zscatter<<<dim3(16),   dim3(256), 0, stream>>>(pred, label, cur, sorted);
    zquery  <<<dim3(4096), dim3(256), 0, stream>>>(sorted, offs, part, counter, out);
}

// Round 14
// 56.344 us; speedup vs baseline: 2.2102x; 2.0141x over previous
//
#include <hip/hip_runtime.h>

constexpr int    N    = 8192;
constexpr int    NB   = 256;                 // z-buckets per set
constexpr float  ZLO  = -4.5f, ZHI = 4.5f;
constexpr float  WINV = NB / (ZHI - ZLO);
constexpr int    QPW  = 4;                   // queries per wave (consecutive in z)
constexpr double SCALE = 274877906944.0;     // 2^38 fixed-point (order-exact sum)

__device__ __forceinline__ int zbucket(float z) {
    float t = fminf(fmaxf((z - ZLO) * WINV, 0.0f), (float)(NB - 1));
    return (int)t;   // monotone, clamped
}

__global__ __launch_bounds__(512) void zinit(unsigned int* __restrict__ cnt) {
    cnt[threadIdx.x] = 0u;
}

// 16 blocks: LDS histogram, merge to global cnt[512] (set0 then set1).
__global__ __launch_bounds__(256) void zhist(
    const float* __restrict__ pred, const float* __restrict__ label,
    unsigned int* __restrict__ cnt)
{
    __shared__ unsigned int h[2 * NB];
    for (int t = threadIdx.x; t < 2 * NB; t += 256) h[t] = 0u;
    __syncthreads();
    #pragma unroll
    for (int k = 0; k < 4; ++k) {
        int i = blockIdx.x * 1024 + k * 256 + threadIdx.x;
        const float* s = (i < N) ? pred : label;
        int j = i & (N - 1);
        int b = zbucket(s[3*j + 2]) + ((i >= N) ? NB : 0);
        atomicAdd(&h[b], 1u);
    }
    __syncthreads();
    for (int t = threadIdx.x; t < 2 * NB; t += 256)
        if (h[t]) atomicAdd(&cnt[t], h[t]);
}

// 1 block: Hillis-Steele scan of 512 counts -> offs[513], cur seeded.
__global__ __launch_bounds__(512) void zscan(
    const unsigned int* __restrict__ cnt, unsigned int* __restrict__ offs,
    unsigned int* __restrict__ cur)
{
    __shared__ unsigned int pre[512];
    int t = threadIdx.x;
    unsigned int c = cnt[t];
    pre[t] = c;
    __syncthreads();
    for (int s = 1; s < 512; s <<= 1) {
        unsigned int add = (t >= s) ? pre[t - s] : 0u;
        __syncthreads();
        pre[t] += add;
        __syncthreads();
    }
    unsigned int ex = pre[t] - c;
    offs[t] = ex;  cur[t] = ex;
    if (t == 511) offs[512] = pre[511];          // = 2N
}

// 16 blocks: scatter points into z-sorted order (set0 [0,N), set1 [N,2N)).
__global__ __launch_bounds__(256) void zscatter(
    const float* __restrict__ pred, const float* __restrict__ label,
    unsigned int* __restrict__ cur, float4* __restrict__ sorted)
{
    #pragma unroll
    for (int k = 0; k < 4; ++k) {
        int i = blockIdx.x * 1024 + k * 256 + threadIdx.x;
        const float* s = (i < N) ? pred : label;
        int j = i & (N - 1);
        float x = s[3*j], y = s[3*j + 1], z = s[3*j + 2];
        int b = zbucket(z) + ((i >= N) ? NB : 0);
        unsigned int slot = atomicAdd(&cur[b], 1u);
        sorted[slot] = make_float4(x, y, z, 0.f);
    }
}

// One wave per query, QPW consecutive queries per wave. No atomics, no fences.
// Seed bound from ~3-bucket span, then coalesced scan of the exact z-window
// [zbucket(qz-rad), zbucket(qz+rad)] (exact: d >= |dz|, zbucket monotone).
__global__ __launch_bounds__(256) void zquery(
    const float4* __restrict__ sorted, const unsigned int* __restrict__ offs,
    float* __restrict__ dout)
{
    int wid = threadIdx.x >> 6, lane = threadIdx.x & 63;
    int qbase = (blockIdx.x * 4 + wid) * QPW;       // [0, 2N), same set within wave

    for (int qq = 0; qq < QPW; ++qq) {
        int qid = qbase + qq;
        float4 q = sorted[qid];
        int tb = (qid < N) ? NB : 0;                // search the OTHER set
        int bq = zbucket(q.z);

        int lo = max(bq - 1, 0), hi = min(bq + 1, NB - 1);
        unsigned int a0 = offs[tb + lo], a1 = offs[tb + hi + 1];
        int w = 1;
        while (a0 == a1 && (lo > 0 || hi < NB - 1)) {   // rare: widen to nonempty
            w <<= 1;
            lo = max(bq - w, 0); hi = min(bq + w, NB - 1);
            a0 = offs[tb + lo]; a1 = offs[tb + hi + 1];
        }
        float best2 = 3.4e38f;
        for (int i = (int)a0 + lane; i < (int)a1; i += 64) {
            float4 p = sorted[i];
            float dx = q.x - p.x, dy = q.y - p.y, dz = q.z - p.z;
            best2 = fminf(best2, dx*dx + dy*dy + dz*dz);
        }
        #pragma unroll
        for (int off = 32; off; off >>= 1)
            best2 = fminf(best2, __shfl_xor(best2, off));

        float rad = sqrtf(best2);
        int l2 = zbucket(q.z - rad), h2 = zbucket(q.z + rad);
        unsigned int s0 = offs[tb + l2], s1 = offs[tb + h2 + 1];
        if (s0 < a0 || s1 > a1) {                   // window wider than seed
            for (int i = (int)s0 + lane; i < (int)s1; i += 64) {
                float4 p = sorted[i];
                float dx = q.x - p.x, dy = q.y - p.y, dz = q.z - p.z;
                best2 = fminf(best2, dx*dx + dy*dy + dz*dz);
            }
            #pragma unroll
            for (int off = 32; off; off >>= 1)
                best2 = fminf(best2, __shfl_xor(best2, off));
        }
        if (lane == 0) dout[qid] = sqrtf(best2);
    }
}

// Fixed-point i64 partial sums (order-exact under within-bucket permutation).
__global__ __launch_bounds__(256) void dreduce(
    const float* __restrict__ dout, long long* __restrict__ part)
{
    long long s = 0;
    #pragma unroll
    for (int k = 0; k < 4; ++k) {
        float d = dout[blockIdx.x * 1024 + k * 256 + threadIdx.x];
        s += (long long)((double)d * SCALE);
    }
    for (int off = 32; off; off >>= 1) s += __shfl_down(s, off);
    __shared__ long long r2[4];
    if ((threadIdx.x & 63) == 0) r2[threadIdx.x >> 6] = s;
    __syncthreads();
    if (threadIdx.x == 0) part[blockIdx.x] = r2[0] + r2[1] + r2[2] + r2[3];
}

__global__ __launch_bounds__(64) void dfinal(
    const long long* __restrict__ part, float* __restrict__ out)
{
    long long s = (threadIdx.x < 16) ? part[threadIdx.x] : 0;
    for (int off = 32; off; off >>= 1) s += __shfl_down(s, off);
    if (threadIdx.x == 0)
        out[0] = (float)((double)s / SCALE / (double)N);  // mean_x + mean_y
}

extern "C" void kernel_launch(void* const* d_in, const int* in_sizes, int n_in,
                              void* d_out, int out_size, void* d_ws, size_t ws_size,
                              hipStream_t stream) {
    const float* pred  = (const float*)d_in[0];
    const float* label = (const float*)d_in[1];
    float* out = (float*)d_out;

    char* ws = (char*)d_ws;
    float4*       sorted = (float4*)ws;                          // 256 KB
    float*        dout   = (float*)(ws + 262144);                // 64 KB
    long long*    part   = (long long*)(ws + 327680);            // 128 B
    unsigned int* offs   = (unsigned int*)(ws + 327936);         // 2052 B
    unsigned int* cnt    = (unsigned int*)(ws + 330240);         // 2048 B
    unsigned int* cur    = (unsigned int*)(ws + 332288);         // 2048 B

    zinit   <<<dim3(1),    dim3(512), 0, stream>>>(cnt);
    zhist   <<<dim3(16),   dim3(256), 0, stream>>>(pred, label, cnt);
    zscan   <<<dim3(1),    dim3(512), 0, stream>>>(cnt, offs, cur);
    zscatter<<<dim3(16),   dim3(256), 0, stream>>>(pred, label, cur, sorted);
    zquery  <<<dim3(1024), dim3(256), 0, stream>>>(sorted, offs, dout);
    dreduce <<<dim3(16),   dim3(256), 0, stream>>>(dout, part);
    dfinal  <<<dim3(1),    dim3(64),  0, stream>>>(part, out);
}

// Round 15
// 43.198 us; speedup vs baseline: 2.8829x; 1.3043x over previous
//
#include <hip/hip_runtime.h>

constexpr int    N    = 8192;
constexpr int    NB   = 256;                 // z-buckets per set
constexpr float  ZLO  = -4.5f, ZHI = 4.5f;
constexpr float  WINV = NB / (ZHI - ZLO);
constexpr double SCALE = 274877906944.0;     // 2^38 fixed-point (order-exact sum)

__device__ __forceinline__ int zbucket(float z) {
    float t = fminf(fmaxf((z - ZLO) * WINV, 0.0f), (float)(NB - 1));
    return (int)t;   // monotone, clamped
}

__device__ __forceinline__ float d2f(float4 q, float4 p) {
    float dx = q.x - p.x, dy = q.y - p.y, dz = q.z - p.z;
    return dx*dx + dy*dy + dz*dz;
}

// 4-wide unrolled coalesced scan of sorted[s0,s1). Tail indices clamp to
// s1-1 (a real in-window point -> valid candidate, min unaffected). 4
// independent loads per lane per step break the load-use latency chain.
__device__ __forceinline__ float scan4(const float4* __restrict__ sorted,
                                       int s0, int s1, float4 q, int lane,
                                       float best2) {
    for (int base = s0; base < s1; base += 256) {
        int i0 = base + lane;
        int i1 = i0 + 64, i2 = i0 + 128, i3 = i0 + 192;
        float4 p0 = sorted[i0 < s1 ? i0 : s1 - 1];
        float4 p1 = sorted[i1 < s1 ? i1 : s1 - 1];
        float4 p2 = sorted[i2 < s1 ? i2 : s1 - 1];
        float4 p3 = sorted[i3 < s1 ? i3 : s1 - 1];
        best2 = fminf(best2, fminf(fminf(d2f(q, p0), d2f(q, p1)),
                                   fminf(d2f(q, p2), d2f(q, p3))));
    }
    return best2;
}

__device__ __forceinline__ float wave_min(float v) {
    #pragma unroll
    for (int off = 32; off; off >>= 1) v = fminf(v, __shfl_xor(v, off));
    return v;
}

// 16 blocks: per-block LDS histogram -> cnt16[block][512], no global atomics.
__global__ __launch_bounds__(256) void zhist(
    const float* __restrict__ pred, const float* __restrict__ label,
    unsigned int* __restrict__ cnt16)
{
    __shared__ unsigned int h[2 * NB];
    for (int t = threadIdx.x; t < 2 * NB; t += 256) h[t] = 0u;
    __syncthreads();
    #pragma unroll
    for (int k = 0; k < 4; ++k) {
        int i = blockIdx.x * 1024 + k * 256 + threadIdx.x;
        const float* s = (i < N) ? pred : label;
        int j = i & (N - 1);
        int b = zbucket(s[3*j + 2]) + ((i >= N) ? NB : 0);
        atomicAdd(&h[b], 1u);
    }
    __syncthreads();
    for (int t = threadIdx.x; t < 2 * NB; t += 256)
        cnt16[blockIdx.x * 512 + t] = h[t];
}

// 1 block: sum 16 partials per bucket, Hillis-Steele scan -> offs[513], cur.
__global__ __launch_bounds__(512) void zscan(
    const unsigned int* __restrict__ cnt16, unsigned int* __restrict__ offs,
    unsigned int* __restrict__ cur)
{
    __shared__ unsigned int pre[512];
    int t = threadIdx.x;
    unsigned int c = 0;
    #pragma unroll
    for (int k = 0; k < 16; ++k) c += cnt16[k * 512 + t];
    pre[t] = c;
    __syncthreads();
    for (int s = 1; s < 512; s <<= 1) {
        unsigned int add = (t >= s) ? pre[t - s] : 0u;
        __syncthreads();
        pre[t] += add;
        __syncthreads();
    }
    unsigned int ex = pre[t] - c;
    offs[t] = ex;  cur[t] = ex;
    if (t == 511) offs[512] = pre[511];          // = 2N
}

// 16 blocks: scatter points into z-sorted order (set0 [0,N), set1 [N,2N)).
__global__ __launch_bounds__(256) void zscatter(
    const float* __restrict__ pred, const float* __restrict__ label,
    unsigned int* __restrict__ cur, float4* __restrict__ sorted)
{
    #pragma unroll
    for (int k = 0; k < 4; ++k) {
        int i = blockIdx.x * 1024 + k * 256 + threadIdx.x;
        const float* s = (i < N) ? pred : label;
        int j = i & (N - 1);
        float x = s[3*j], y = s[3*j + 1], z = s[3*j + 2];
        int b = zbucket(z) + ((i >= N) ? NB : 0);
        unsigned int slot = atomicAdd(&cur[b], 1u);
        sorted[slot] = make_float4(x, y, z, 0.f);
    }
}

// One wave per query (4 queries/block, grid 4096). Wave-uniform branches,
// 4-wide unrolled coalesced scans, delta-only second pass. No atomics/fences.
__global__ __launch_bounds__(256) void zquery(
    const float4* __restrict__ sorted, const unsigned int* __restrict__ offs,
    float* __restrict__ dout)
{
    int wid = threadIdx.x >> 6, lane = threadIdx.x & 63;
    int qid = blockIdx.x * 4 + wid;                 // [0, 2N)
    float4 q = sorted[qid];
    int tb = (qid < N) ? NB : 0;                    // search the OTHER set
    int bq = zbucket(q.z);

    int lo = max(bq - 1, 0), hi = min(bq + 1, NB - 1);
    int a0 = offs[tb + lo], a1 = offs[tb + hi + 1];
    int w = 1;
    while (a0 == a1 && (lo > 0 || hi < NB - 1)) {   // rare: widen to nonempty
        w <<= 1;
        lo = max(bq - w, 0); hi = min(bq + w, NB - 1);
        a0 = offs[tb + lo]; a1 = offs[tb + hi + 1];
    }
    float best2 = wave_min(scan4(sorted, a0, a1, q, lane, 3.4e38f));

    float rad = sqrtf(best2);
    int l2 = zbucket(q.z - rad), h2 = zbucket(q.z + rad);
    int s0 = offs[tb + l2], s1 = offs[tb + h2 + 1];
    bool extra = (s0 < a0) | (s1 > a1);
    if (s0 < a0) best2 = scan4(sorted, s0, a0, q, lane, best2);
    if (s1 > a1) best2 = scan4(sorted, a1, s1, q, lane, best2);
    if (extra)   best2 = wave_min(best2);
    if (lane == 0) dout[qid] = sqrtf(best2);
}

// 1 block x 1024: fixed-point i64 sum of all 16K distances -> out[0].
__global__ __launch_bounds__(1024) void dsum(
    const float* __restrict__ dout, float* __restrict__ out)
{
    long long s = 0;
    #pragma unroll
    for (int k = 0; k < 16; ++k) {
        float d = dout[k * 1024 + threadIdx.x];
        s += (long long)((double)d * SCALE);
    }
    for (int off = 32; off; off >>= 1) s += __shfl_down(s, off);
    __shared__ long long r2[16];
    if ((threadIdx.x & 63) == 0) r2[threadIdx.x >> 6] = s;
    __syncthreads();
    if (threadIdx.x == 0) {
        long long t = 0;
        #pragma unroll
        for (int i = 0; i < 16; ++i) t += r2[i];
        out[0] = (float)((double)t / SCALE / (double)N);  // mean_x + mean_y
    }
}

extern "C" void kernel_launch(void* const* d_in, const int* in_sizes, int n_in,
                              void* d_out, int out_size, void* d_ws, size_t ws_size,
                              hipStream_t stream) {
    const float* pred  = (const float*)d_in[0];
    const float* label = (const float*)d_in[1];
    float* out = (float*)d_out;

    char* ws = (char*)d_ws;
    float4*       sorted = (float4*)ws;                          // 256 KB
    float*        dout   = (float*)(ws + 262144);                // 64 KB
    unsigned int* cnt16  = (unsigned int*)(ws + 327680);         // 32 KB
    unsigned int* offs   = (unsigned int*)(ws + 360448);         // 2052 B
    unsigned int* cur    = (unsigned int*)(ws + 362752);         // 2048 B

    zhist   <<<dim3(16),   dim3(256),  0, stream>>>(pred, label, cnt16);
    zscan   <<<dim3(1),    dim3(512),  0, stream>>>(cnt16, offs, cur);
    zscatter<<<dim3(16),   dim3(256),  0, stream>>>(pred, label, cur, sorted);
    zquery  <<<dim3(4096), dim3(256),  0, stream>>>(sorted, offs, dout);
    dsum    <<<dim3(1),    dim3(1024), 0, stream>>>(dout, out);
}

// Round 16
// 20.355 us; speedup vs baseline: 6.1181x; 2.1222x over previous
//
#include <hip/hip_runtime.h>

constexpr int N    = 8192;
constexpr int BLK  = 256;
constexpr int BX   = 256;      // x-points per block (P=16 -> halves ds_reads/eval)
constexpr int BY   = 1024;     // y-points per block (keeps 512 blocks = 2/CU)
constexpr int NYR  = N / BY;   // 8 y-ranges
constexpr int P    = 16;       // x-points per thread
constexpr int NSL  = 16;       // y-slices per block
constexpr int SY   = BY / NSL; // 64 y per slice
constexpr int SPAD = SY + 1;   // 65 float4s: +4 banks per slice row
constexpr int RPAD = BX + 4;   // 260: +4 banks per slice row

// grid 512: dir = b>>8, xbk = (b>>3)&31, yr = b&7.
// Thread (u = t&15, ys = t>>4) owns x {xbk*256 + k*16 + u, k<16} and scans
// y-slice ys (64 pts) from LDS. 256 partial mins -> minbuf[yr][dir*N + x].
__global__ __launch_bounds__(BLK) void chamfer_stage1(
    const float* __restrict__ pred, const float* __restrict__ label,
    float* __restrict__ minbuf)
{
    int b   = blockIdx.x;
    int dir = b >> 8;
    int xbk = (b >> 3) & 31;
    int yr  = b & 7;

    const float* A = dir ? label : pred;   // query set
    const float* B = dir ? pred  : label;  // target set

    __shared__ float4 sy[NSL * SPAD];      // 16.6 KB
    __shared__ float  red[NSL * RPAD];     // 16.6 KB

    int u  = threadIdx.x & 15;
    int ys = threadIdx.x >> 4;

    float cxa[P], cxb[P], cxc[P], xn[P], m[P];
    #pragma unroll
    for (int k = 0; k < P; ++k) {
        int idx = xbk * BX + k * 16 + u;
        float a = A[3*idx], c = A[3*idx+1], d = A[3*idx+2];
        cxa[k] = -2.f * a;  cxb[k] = -2.f * c;  cxc[k] = -2.f * d;
        xn[k] = a*a + c*c + d*d;
        m[k]  = 3.4e38f;
    }

    for (int i = threadIdx.x; i < BY; i += BLK) {    // 4 staging iterations
        int g = yr * BY + i;
        float a = B[3*g], c = B[3*g+1], d = B[3*g+2];
        sy[(i >> 6) * SPAD + (i & (SY-1))] = make_float4(a, c, d, a*a + c*c + d*d);
    }
    __syncthreads();

    const float4* s = &sy[ys * SPAD];
    #pragma unroll 4
    for (int j = 0; j < SY; j += 2) {                // 32 iters, 32 evals each
        float4 ya = s[j], yb = s[j + 1];
        #pragma unroll
        for (int k = 0; k < P; ++k) {
            float sa = fmaf(cxa[k], ya.x, fmaf(cxb[k], ya.y, fmaf(cxc[k], ya.z, ya.w)));
            float sb = fmaf(cxa[k], yb.x, fmaf(cxb[k], yb.y, fmaf(cxc[k], yb.z, yb.w)));
            m[k] = fminf(fminf(sa, sb), m[k]);       // v_min3_f32
        }
    }

    #pragma unroll
    for (int k = 0; k < P; ++k)
        red[ys * RPAD + k * 16 + u] = fmaxf(m[k] + xn[k], 0.f);
    __syncthreads();

    {   // all 256 threads: 16-way cross-slice min for one x-column each
        float v = red[threadIdx.x];
        #pragma unroll
        for (int q = 1; q < NSL; ++q)
            v = fminf(v, red[q * RPAD + threadIdx.x]);
        minbuf[yr * (2 * N) + dir * N + xbk * BX + threadIdx.x] = v;
    }
}

// 16 blocks x 256 threads: column float4 min over 8 ranges (coalesced),
// sqrt, fixed-order block sum -> bsum[block].
__global__ __launch_bounds__(256) void chamfer_stage2(
    const float4* __restrict__ minbuf4, float* __restrict__ bsum)
{
    int g = blockIdx.x * 256 + threadIdx.x;   // float4 index in [0, 4096)
    float4 v = minbuf4[g];
    #pragma unroll
    for (int r = 1; r < NYR; ++r) {
        float4 w = minbuf4[r * 4096 + g];
        v.x = fminf(v.x, w.x); v.y = fminf(v.y, w.y);
        v.z = fminf(v.z, w.z); v.w = fminf(v.w, w.w);
    }
    float s = sqrtf(v.x) + sqrtf(v.y) + sqrtf(v.z) + sqrtf(v.w);
    for (int off = 32; off; off >>= 1) s += __shfl_down(s, off);
    __shared__ float r2[4];
    if ((threadIdx.x & 63) == 0) r2[threadIdx.x >> 6] = s;
    __syncthreads();
    if (threadIdx.x == 0)
        bsum[blockIdx.x] = r2[0] + r2[1] + r2[2] + r2[3];
}

// one wave: final fixed-order sum of 16 block partials, scale by 1/N.
__global__ __launch_bounds__(64) void chamfer_stage3(
    const float* __restrict__ bsum, float* __restrict__ out)
{
    float s = (threadIdx.x < 16) ? bsum[threadIdx.x] : 0.f;
    for (int off = 32; off; off >>= 1) s += __shfl_down(s, off);
    if (threadIdx.x == 0) out[0] = s * (1.0f / N);   // mean_x(min)+mean_y(min)
}

extern "C" void kernel_launch(void* const* d_in, const int* in_sizes, int n_in,
                              void* d_out, int out_size, void* d_ws, size_t ws_size,
                              hipStream_t stream) {
    const float* pred  = (const float*)d_in[0];
    const float* label = (const float*)d_in[1];
    float* out    = (float*)d_out;
    float* minbuf = (float*)d_ws;                 // NYR*2N floats = 512 KB
    float* bsum   = minbuf + NYR * 2 * N;         // 16 floats

    chamfer_stage1<<<dim3(2 * (N / BX) * NYR), dim3(BLK), 0, stream>>>(pred, label, minbuf);
    chamfer_stage2<<<dim3(16), dim3(256), 0, stream>>>((const float4*)minbuf, bsum);
    chamfer_stage3<<<dim3(1), dim3(64), 0, stream>>>(bsum, out);
}